// Round 1
// baseline (9304.037 us; speedup 1.0000x reference)
//
#include <hip/hip_runtime.h>

#define S_ 32
#define O_ 64
#define T_ 91
#define C_ 128
#define H_ 8
#define HD_ 16

// Fused per-(batch, head) masked MHA (QKV + scores + softmax + P@V), pre-projection.
// Generic over batch decomposition via stride args:
//   x token n element c at: x[outer*xo + inner*xi + n*xn + c]
//   mask token n at:        mask[outer*mo + inner*mi + n*mn]
// where outer = b / inner_n, inner = b % inner_n, b = blockIdx.x.
// Output y is (B, N, C) contiguous; this block writes columns [h*16, h*16+16).
__global__ __launch_bounds__(256) void attn_fused(
    const float* __restrict__ x, const int* __restrict__ mask,
    const float* __restrict__ Wqkv, float* __restrict__ y,
    int N, int inner_n,
    long xo, long xi, long xn,
    long mo, long mi, long mn)
{
    extern __shared__ float smem[];
    const int b = blockIdx.x;
    const int h = blockIdx.y;
    const int tid = threadIdx.x;
    const int outer = b / inner_n;
    const int inner = b - outer * inner_n;
    const long xb = (long)outer * xo + (long)inner * xi;
    const long mb = (long)outer * mo + (long)inner * mi;

    float* s_qkv = smem;                    // 3*N*HD floats (q | k | v)
    float* s_x   = smem + 3 * N * HD_;      // N*C floats; later reused as scores (N*N <= N*C since N<=C)
    int*   s_m   = (int*)(s_x + N * C_);    // N ints

    // Phase A: stage x tile + mask into LDS
    for (int idx = tid; idx < N * C_; idx += 256) {
        int n = idx >> 7, c = idx & 127;
        s_x[idx] = x[xb + (long)n * xn + c];
    }
    for (int idx = tid; idx < N; idx += 256)
        s_m[idx] = (mask[mb + (long)idx * mn] != 0);
    __syncthreads();

    // Phase B: qkv for this head: out (n, which*16+dd) = dot(x_n, Wqkv_row)
    for (int idx = tid; idx < N * 3 * HD_; idx += 256) {
        int n = idx / (3 * HD_);
        int d = idx - n * (3 * HD_);
        int which = d / HD_, dd = d - which * HD_;
        const float4* wr = (const float4*)(Wqkv + (long)(which * C_ + h * HD_ + dd) * C_);
        const float4* xr = (const float4*)(s_x + n * C_);
        float acc = 0.f;
        #pragma unroll
        for (int k = 0; k < C_ / 4; ++k) {
            float4 a = xr[k], w = wr[k];
            acc += a.x * w.x + a.y * w.y + a.z * w.z + a.w * w.w;
        }
        s_qkv[which * N * HD_ + n * HD_ + dd] = acc;
    }
    __syncthreads();

    // Phase C: scores into s_x region (x tile no longer needed)
    float* s_s = s_x;
    const float scale = 0.25f;  // hd^-0.5 = 1/sqrt(16)
    for (int idx = tid; idx < N * N; idx += 256) {
        int i = idx / N, j = idx - i * N;
        float v;
        if (!s_m[i]) {
            v = 0.f;                    // dead row -> all-zero scores -> uniform softmax
        } else if (!s_m[j]) {
            v = -1e30f;                 // masked key
        } else {
            const float* qi = s_qkv + i * HD_;
            const float* kj = s_qkv + N * HD_ + j * HD_;
            float acc = 0.f;
            #pragma unroll
            for (int d = 0; d < HD_; ++d) acc += qi[d] * kj[d];
            v = acc * scale;
        }
        s_s[idx] = v;
    }
    __syncthreads();

    // Phase D: row softmax (thread-per-row; v1 simplicity)
    for (int i = tid; i < N; i += 256) {
        float* row = s_s + i * N;
        float mx = -1e30f;
        for (int j = 0; j < N; ++j) mx = fmaxf(mx, row[j]);
        float sum = 0.f;
        for (int j = 0; j < N; ++j) { float e = __expf(row[j] - mx); row[j] = e; sum += e; }
        float inv = 1.f / sum;
        for (int j = 0; j < N; ++j) row[j] *= inv;
    }
    __syncthreads();

    // Phase E: out = P @ V, write head slice
    for (int idx = tid; idx < N * HD_; idx += 256) {
        int n = idx / HD_, c = idx - n * HD_;
        const float* vv = s_qkv + 2 * N * HD_;
        float acc = 0.f;
        for (int j = 0; j < N; ++j) acc += s_s[n * N + j] * vv[j * HD_ + c];
        y[((long)b * N + n) * C_ + h * HD_ + c] = acc;
    }
}

// out[r, c] = dot(A[r, :], W[c, :]) + bias[c]; rows are C_=128 wide, K=128.
// Safe to run in-place (out == A): each block reads its 32 rows fully (all K
// chunks, ending in a barrier) before the epilogue writes them.
__global__ __launch_bounds__(256) void proj_kernel(
    const float* __restrict__ A, const float* __restrict__ W,
    const float* __restrict__ bias, float* __restrict__ out, int nrows)
{
    __shared__ float As[32][33];
    __shared__ float Ws[128][33];
    const int tid = threadIdx.x;
    const int row0 = blockIdx.x * 32;
    const int tcol = tid & 31;   // 32 col-groups of 4 -> 128 cols
    const int trow = tid >> 5;   // 8 row-groups of 4 -> 32 rows
    float acc[4][4] = {};

    for (int k0 = 0; k0 < C_; k0 += 32) {
        {
            int idx = tid * 4;                 // 1024 elems, 4/thread
            int r = idx >> 5, kk = idx & 31;
            float4 v = *(const float4*)(A + (long)(row0 + r) * C_ + k0 + kk);
            As[r][kk] = v.x; As[r][kk + 1] = v.y; As[r][kk + 2] = v.z; As[r][kk + 3] = v.w;
        }
        #pragma unroll
        for (int i = 0; i < 4; ++i) {          // 4096 elems, 16/thread
            int idx = tid * 4 + i * 1024;
            int c = idx >> 5, kk = idx & 31;
            float4 v = *(const float4*)(W + (long)c * C_ + k0 + kk);
            Ws[c][kk] = v.x; Ws[c][kk + 1] = v.y; Ws[c][kk + 2] = v.z; Ws[c][kk + 3] = v.w;
        }
        __syncthreads();
        #pragma unroll
        for (int kk = 0; kk < 32; ++kk) {
            float a[4], bb[4];
            #pragma unroll
            for (int i = 0; i < 4; ++i) a[i] = As[trow * 4 + i][kk];
            #pragma unroll
            for (int j = 0; j < 4; ++j) bb[j] = Ws[tcol * 4 + j][kk];
            #pragma unroll
            for (int i = 0; i < 4; ++i)
                #pragma unroll
                for (int j = 0; j < 4; ++j) acc[i][j] += a[i] * bb[j];
        }
        __syncthreads();
    }
    #pragma unroll
    for (int i = 0; i < 4; ++i) {
        int r = row0 + trow * 4 + i;
        #pragma unroll
        for (int j = 0; j < 4; ++j) {
            int c = tcol * 4 + j;
            out[(long)r * C_ + c] = acc[i][j] + bias[c];
        }
    }
}

extern "C" void kernel_launch(void* const* d_in, const int* in_sizes, int n_in,
                              void* d_out, int out_size, void* d_ws, size_t ws_size,
                              hipStream_t stream) {
    const float* x       = (const float*)d_in[0];
    const int*   mask    = (const int*)d_in[1];   // bool -> int32 per harness rules
    const float* Wqkv_a  = (const float*)d_in[2];
    const float* Wproj_a = (const float*)d_in[3];
    const float* bproj_a = (const float*)d_in[4];
    const float* Wqkv_t  = (const float*)d_in[5];
    const float* Wproj_t = (const float*)d_in[6];
    const float* bproj_t = (const float*)d_in[7];
    float* out = (float*)d_out;
    float* xa  = (float*)d_ws;   // 95.4 MB scratch: post-agent-proj tensor (S,T,O,C)

    const int NROWS = S_ * O_ * T_;   // 186368 tokens, % 32 == 0

    // K1: agent attention (batch b = s*T + t, tokens = objects, N=64) -> y_a in d_out (S*T, O, C)
    {
        dim3 grid(S_ * T_, H_);
        size_t lds = (size_t)(3 * O_ * HD_ + O_ * C_ + O_) * 4;
        attn_fused<<<grid, 256, lds, stream>>>(x, mask, Wqkv_a, out, O_, T_,
            (long)O_ * T_ * C_, (long)C_, (long)T_ * C_,   // x: [s][o][t][c], o is token
            (long)O_ * T_, 1L, (long)T_);                  // mask: [s][o][t]
    }
    // K2: proj_a: xa = y_a @ Wproj_a^T + b  -> ws, layout (S,T,O,C)
    proj_kernel<<<NROWS / 32, 256, 0, stream>>>(out, Wproj_a, bproj_a, xa, NROWS);

    // K3: time attention (batch b = s*O + o, tokens = timesteps, N=91) -> y_t in d_out (S,O,T,C)
    {
        dim3 grid(S_ * O_, H_);
        size_t lds = (size_t)(3 * T_ * HD_ + T_ * C_ + T_) * 4;   // 64,428 B <= 64 KiB
        attn_fused<<<grid, 256, lds, stream>>>(xa, mask, Wqkv_t, out, T_, O_,
            (long)T_ * O_ * C_, (long)C_, (long)O_ * C_,   // xa: [s][t][o][c], t is token
            (long)O_ * T_, (long)T_, 1L);                  // mask: [s][o][t]
    }
    // K4: proj_t in-place on d_out -> final (S,O,T,C)
    proj_kernel<<<NROWS / 32, 256, 0, stream>>>(out, Wproj_t, bproj_t, out, NROWS);
}

// Round 2
// 2191.056 us; speedup vs baseline: 4.2464x; 4.2464x over previous
//
#include <hip/hip_runtime.h>

#define S_ 32
#define O_ 64
#define T_ 91
#define C_ 128
#define H_ 8
#define HD_ 16
#define NCHUNK 4
#define SC_ (S_ / NCHUNK)             // 8 scenes per chunk
#define ROWS_CHUNK (SC_ * O_ * T_)    // 46592 tokens per chunk

// ---------------------------------------------------------------------------
// Generic tiled GEMM: out[lr][c] = dot(A_row(R), W[c]) + bias[c]
//   R = row0 + lr (lr = chunk-local row), gather:
//   off(R) = (R/DA)*s1 + ((R/DB)%MB)*s2 + (R%MC)*s3     (float offset into A)
// Tile: 64 rows x 128 cols, K = C_ = 128, BK = 32. 256 threads, 4x8 acc/thread.
// In-place safe when out==A(+identity gather) and gridDim.y==1: each block
// reads only its own 64 rows (all K) before the epilogue writes them.
// ---------------------------------------------------------------------------
__global__ __launch_bounds__(256) void gemm_rows(
    const float* __restrict__ A, const float* __restrict__ W,
    const float* __restrict__ bias, float* __restrict__ out,
    int row0, int ncols,
    int DA, long s1, int DB, int MB, long s2, int MC, long s3)
{
    __shared__ float As[64][33];
    __shared__ float Ws[128][33];
    const int tid = threadIdx.x;
    const int lr0 = blockIdx.x * 64;
    const int c0 = blockIdx.y * 128;
    const int tcol = tid & 15;    // cols c = tcol + 16*j, j=0..7
    const int trow = tid >> 4;    // rows r = trow*4 + i, i=0..3
    float acc[4][8] = {};

    for (int k0 = 0; k0 < C_; k0 += 32) {
        #pragma unroll
        for (int i = 0; i < 2; ++i) {                  // A tile: 64x32
            int idx = (tid + i * 256) * 4;
            int r = idx >> 5, kk = idx & 31;
            int R = row0 + lr0 + r;
            long off = (long)(R / DA) * s1 + (long)((R / DB) % MB) * s2 + (long)(R % MC) * s3;
            float4 v = *(const float4*)(A + off + k0 + kk);
            As[r][kk] = v.x; As[r][kk + 1] = v.y; As[r][kk + 2] = v.z; As[r][kk + 3] = v.w;
        }
        #pragma unroll
        for (int i = 0; i < 4; ++i) {                  // W tile: 128x32
            int idx = (tid + i * 256) * 4;
            int cc = idx >> 5, kk = idx & 31;
            float4 v = *(const float4*)(W + (long)(c0 + cc) * C_ + k0 + kk);
            Ws[cc][kk] = v.x; Ws[cc][kk + 1] = v.y; Ws[cc][kk + 2] = v.z; Ws[cc][kk + 3] = v.w;
        }
        __syncthreads();
        #pragma unroll
        for (int kk = 0; kk < 32; ++kk) {
            float a[4], b[8];
            #pragma unroll
            for (int i = 0; i < 4; ++i) a[i] = As[trow * 4 + i][kk];
            #pragma unroll
            for (int j = 0; j < 8; ++j) b[j] = Ws[tcol + 16 * j][kk];
            #pragma unroll
            for (int i = 0; i < 4; ++i)
                #pragma unroll
                for (int j = 0; j < 8; ++j) acc[i][j] += a[i] * b[j];
        }
        __syncthreads();
    }
    #pragma unroll
    for (int i = 0; i < 4; ++i) {
        long r = lr0 + trow * 4 + i;
        #pragma unroll
        for (int j = 0; j < 8; ++j) {
            int c = c0 + tcol + 16 * j;
            float v = acc[i][j];
            if (bias) v += bias[c];
            out[r * ncols + c] = v;
        }
    }
}

// ---------------------------------------------------------------------------
// Attention core (per batch, per head). qkv: chunk-local [bl*N+n][384]
// (q | k | v each 128 wide, head slice h*16). K held in per-lane registers
// (lane j owns k_j; lanes 0..N-65 also own k_{j+64}); q broadcast from LDS;
// row softmax via __shfl_xor reductions; P -> LDS (stride 92, conflict-free);
// PV with broadcast-only LDS reads. y: chunk-local [bl*N+n][128], head slice.
// ---------------------------------------------------------------------------
__global__ __launch_bounds__(256) void attn_kernel(
    const float* __restrict__ qkv, const int* __restrict__ mask,
    float* __restrict__ y, int N, int b0, int bdiv, long m1, long m2)
{
    extern __shared__ float sm[];
    const int bl = blockIdx.x, h = blockIdx.y;
    const int tid = threadIdx.x, lane = tid & 63, w = tid >> 6;
    const int b = b0 + bl;
    const int sidx = b / bdiv, u = b - sidx * bdiv;
    const long mbase = (long)sidx * (O_ * T_) + (long)u * m1;

    float* s_q = sm;                       // N*16
    float* s_v = s_q + N * HD_;            // N*16
    float* s_p = s_v + N * HD_;            // N*92
    int*   s_m = (int*)(s_p + N * 92);     // N

    const float* qb = qkv + (long)bl * N * 384;
    for (int idx = tid; idx < N * HD_; idx += 256) {
        int n = idx >> 4, d = idx & 15;
        s_q[idx] = qb[n * 384 + h * HD_ + d];
        s_v[idx] = qb[n * 384 + 256 + h * HD_ + d];
    }
    for (int idx = tid; idx < N; idx += 256)
        s_m[idx] = (mask[mbase + (long)idx * m2] != 0);

    const int j1 = lane, j2 = lane + 64;
    const bool has2 = (j2 < N);
    float kr1[HD_], kr2[HD_];
    {
        const float4* kb = (const float4*)(qb + (long)j1 * 384 + 128 + h * HD_);
        #pragma unroll
        for (int t = 0; t < 4; ++t) {
            float4 f = kb[t];
            kr1[t * 4] = f.x; kr1[t * 4 + 1] = f.y; kr1[t * 4 + 2] = f.z; kr1[t * 4 + 3] = f.w;
        }
        if (has2) {
            const float4* kb2 = (const float4*)(qb + (long)j2 * 384 + 128 + h * HD_);
            #pragma unroll
            for (int t = 0; t < 4; ++t) {
                float4 f = kb2[t];
                kr2[t * 4] = f.x; kr2[t * 4 + 1] = f.y; kr2[t * 4 + 2] = f.z; kr2[t * 4 + 3] = f.w;
            }
        } else {
            #pragma unroll
            for (int t = 0; t < HD_; ++t) kr2[t] = 0.f;
        }
    }
    __syncthreads();
    const int mj1 = s_m[j1];
    const int mj2 = has2 ? s_m[j2] : 0;

    for (int i = w; i < N; i += 4) {       // each wave owns rows i = w, w+4, ...
        const float4* qp = (const float4*)(s_q + i * HD_);
        float qv[HD_];
        #pragma unroll
        for (int t = 0; t < 4; ++t) {
            float4 f = qp[t];
            qv[t * 4] = f.x; qv[t * 4 + 1] = f.y; qv[t * 4 + 2] = f.z; qv[t * 4 + 3] = f.w;
        }
        float d1 = 0.f, d2 = 0.f;
        #pragma unroll
        for (int d = 0; d < HD_; ++d) { d1 += qv[d] * kr1[d]; d2 += qv[d] * kr2[d]; }
        const int mi = s_m[i];             // broadcast read
        // dead row (mi==0): all scores 0 -> uniform softmax over all N
        float a1 = mi ? (mj1 ? d1 * 0.25f : -1e30f) : 0.f;
        float a2 = mi ? (mj2 ? d2 * 0.25f : -1e30f) : 0.f;
        float mloc = fmaxf(a1, has2 ? a2 : -1e30f);
        #pragma unroll
        for (int off = 32; off; off >>= 1) mloc = fmaxf(mloc, __shfl_xor(mloc, off, 64));
        float e1 = __expf(a1 - mloc);
        float e2 = has2 ? __expf(a2 - mloc) : 0.f;
        float ss = e1 + e2;
        #pragma unroll
        for (int off = 32; off; off >>= 1) ss += __shfl_xor(ss, off, 64);
        float inv = 1.f / ss;
        s_p[i * 92 + j1] = e1 * inv;
        if (has2) s_p[i * 92 + j2] = e2 * inv;
    }
    __syncthreads();

    for (int idx = tid; idx < N * HD_; idx += 256) {
        int n = idx >> 4, c = idx & 15;
        const float* pr = s_p + n * 92;
        float acc = 0.f;
        #pragma unroll 4
        for (int j = 0; j < N; ++j) acc += pr[j] * s_v[j * HD_ + c];
        y[((long)bl * N + n) * C_ + h * HD_ + c] = acc;
    }
}

extern "C" void kernel_launch(void* const* d_in, const int* in_sizes, int n_in,
                              void* d_out, int out_size, void* d_ws, size_t ws_size,
                              hipStream_t stream) {
    const float* x       = (const float*)d_in[0];
    const int*   mask    = (const int*)d_in[1];
    const float* Wqkv_a  = (const float*)d_in[2];
    const float* Wproj_a = (const float*)d_in[3];
    const float* bproj_a = (const float*)d_in[4];
    const float* Wqkv_t  = (const float*)d_in[5];
    const float* Wproj_t = (const float*)d_in[6];
    const float* bproj_t = (const float*)d_in[7];
    float* out   = (float*)d_out;
    float* qkvws = (float*)d_ws;   // 46592*384*4 = 71.6 MB per chunk (reused)

    const dim3 gq(ROWS_CHUNK / 64, 3);   // qkv gemm
    const dim3 gp(ROWS_CHUNK / 64, 1);   // proj gemm
    const size_t lds1 = (size_t)O_ * 125 * 4;   // 32 KB
    const size_t lds2 = (size_t)T_ * 125 * 4;   // 45.5 KB

    // ---- Pass 1: agent attention. Token order (s, t, o); rows chunked by scenes.
    for (int c = 0; c < NCHUNK; ++c) {
        const int rowbase = c * ROWS_CHUNK;
        // qkv1: gather x[(s,o,t)] rows in (s,t,o) order
        gemm_rows<<<gq, 256, 0, stream>>>(x, Wqkv_a, nullptr, qkvws,
            rowbase, 3 * C_,
            /*DA=*/T_ * O_, /*s1=*/(long)O_ * T_ * C_,
            /*DB=*/O_, /*MB=*/T_, /*s2=*/(long)C_,
            /*MC=*/O_, /*s3=*/(long)T_ * C_);
        // attn1: batches (s,t) local, N=64 objects; y -> d_out chunk rows
        dim3 ga(SC_ * T_, H_);
        attn_kernel<<<ga, 256, lds1, stream>>>(qkvws, mask, out + (long)rowbase * C_,
            O_, /*b0=*/c * SC_ * T_, /*bdiv=*/T_, /*m1=*/1L, /*m2=*/(long)T_);
        // proj1: in-place on d_out chunk rows -> xa (stored (s,t,o) order)
        gemm_rows<<<gp, 256, 0, stream>>>(out + (long)rowbase * C_, Wproj_a, bproj_a,
            out + (long)rowbase * C_,
            0, C_, /*DA=*/1, /*s1=*/(long)C_, /*DB=*/1, /*MB=*/1, /*s2=*/0L, /*MC=*/1, /*s3=*/0L);
    }

    // ---- Pass 2: time attention. Token order (s, o, t); xa lives in d_out (s,t,o).
    for (int c = 0; c < NCHUNK; ++c) {
        const int rowbase = c * ROWS_CHUNK;
        // qkv2: gather xa rows ((s,t,o)-ordered buffer) in (s,o,t) order
        gemm_rows<<<gq, 256, 0, stream>>>(out, Wqkv_t, nullptr, qkvws,
            rowbase, 3 * C_,
            /*DA=*/O_ * T_, /*s1=*/(long)T_ * O_ * C_,
            /*DB=*/T_, /*MB=*/O_, /*s2=*/(long)C_,
            /*MC=*/T_, /*s3=*/(long)O_ * C_);
        // attn2: batches (s,o) local, N=91 timesteps; y -> d_out chunk rows
        // (overwrites this chunk's xa rows, already consumed by qkv2 above)
        dim3 ga(SC_ * O_, H_);
        attn_kernel<<<ga, 256, lds2, stream>>>(qkvws, mask, out + (long)rowbase * C_,
            T_, /*b0=*/c * SC_ * O_, /*bdiv=*/O_, /*m1=*/(long)T_, /*m2=*/1L);
        // proj2: in-place -> final output (s,o,t,c)
        gemm_rows<<<gp, 256, 0, stream>>>(out + (long)rowbase * C_, Wproj_t, bproj_t,
            out + (long)rowbase * C_,
            0, C_, /*DA=*/1, /*s1=*/(long)C_, /*DB=*/1, /*MB=*/1, /*s2=*/0L, /*MC=*/1, /*s3=*/0L);
    }
}

// Round 3
// 1734.164 us; speedup vs baseline: 5.3651x; 1.2635x over previous
//
#include <hip/hip_runtime.h>

#define S_ 32
#define O_ 64
#define T_ 91
#define C_ 128
#define H_ 8
#define HD_ 16
#define NCHUNK 4
#define SC_ (S_ / NCHUNK)             // 8 scenes per chunk
#define ROWS_CHUNK (SC_ * O_ * T_)    // 46592 tokens per chunk
#define PSTR 92                       // s_p row stride (even -> b64-aligned, 2-way banks)

// ---------------------------------------------------------------------------
// Generic tiled GEMM: out[lr][c] = dot(A_row(R), W[c]) + bias[c]
//   R = row0 + lr, gather: off(R) = (R/DA)*s1 + ((R/DB)%MB)*s2 + (R%MC)*s3
// 64x128 tile, K=128, BK=32, 256 threads, 4x8 acc. In-place safe when out==A,
// identity gather, gridDim.y==1 (block reads its 64 rows fully before writing).
// ---------------------------------------------------------------------------
__global__ __launch_bounds__(256) void gemm_rows(
    const float* __restrict__ A, const float* __restrict__ W,
    const float* __restrict__ bias, float* __restrict__ out,
    int row0, int ncols,
    int DA, long s1, int DB, int MB, long s2, int MC, long s3)
{
    __shared__ float As[64][33];
    __shared__ float Ws[128][33];
    const int tid = threadIdx.x;
    const int lr0 = blockIdx.x * 64;
    const int c0 = blockIdx.y * 128;
    const int tcol = tid & 15;
    const int trow = tid >> 4;
    float acc[4][8] = {};

    for (int k0 = 0; k0 < C_; k0 += 32) {
        #pragma unroll
        for (int i = 0; i < 2; ++i) {
            int idx = (tid + i * 256) * 4;
            int r = idx >> 5, kk = idx & 31;
            int R = row0 + lr0 + r;
            long off = (long)(R / DA) * s1 + (long)((R / DB) % MB) * s2 + (long)(R % MC) * s3;
            float4 v = *(const float4*)(A + off + k0 + kk);
            As[r][kk] = v.x; As[r][kk + 1] = v.y; As[r][kk + 2] = v.z; As[r][kk + 3] = v.w;
        }
        #pragma unroll
        for (int i = 0; i < 4; ++i) {
            int idx = (tid + i * 256) * 4;
            int cc = idx >> 5, kk = idx & 31;
            float4 v = *(const float4*)(W + (long)(c0 + cc) * C_ + k0 + kk);
            Ws[cc][kk] = v.x; Ws[cc][kk + 1] = v.y; Ws[cc][kk + 2] = v.z; Ws[cc][kk + 3] = v.w;
        }
        __syncthreads();
        #pragma unroll
        for (int kk = 0; kk < 32; ++kk) {
            float a[4], b[8];
            #pragma unroll
            for (int i = 0; i < 4; ++i) a[i] = As[trow * 4 + i][kk];
            #pragma unroll
            for (int j = 0; j < 8; ++j) b[j] = Ws[tcol + 16 * j][kk];
            #pragma unroll
            for (int i = 0; i < 4; ++i)
                #pragma unroll
                for (int j = 0; j < 8; ++j) acc[i][j] += a[i] * b[j];
        }
        __syncthreads();
    }
    #pragma unroll
    for (int i = 0; i < 4; ++i) {
        long r = lr0 + trow * 4 + i;
        #pragma unroll
        for (int j = 0; j < 8; ++j) {
            int c = c0 + tcol + 16 * j;
            float v = acc[i][j];
            if (bias) v += bias[c];
            out[r * ncols + c] = v;
        }
    }
}

// ---------------------------------------------------------------------------
// Attention core (per batch, per head). qkv: chunk-local [bl*N+n][384].
// K in per-lane regs (lane j owns k_j, k_{j+64}); q,V staged in LDS;
// softmax without max-subtract (scores bounded ~|8| << 88); sum via shfl_xor;
// PV register-blocked: thread = rows {rg, rg+64} x cols [cg*4, cg*4+4).
// ---------------------------------------------------------------------------
__global__ __launch_bounds__(256) void attn_kernel(
    const float* __restrict__ qkv, const int* __restrict__ mask,
    float* __restrict__ y, int N, int b0, int bdiv, long m1, long m2)
{
    extern __shared__ float sm[];
    const int bl = blockIdx.x, h = blockIdx.y;
    const int tid = threadIdx.x, lane = tid & 63, w = tid >> 6;
    const int b = b0 + bl;
    const int sidx = b / bdiv, u = b - sidx * bdiv;
    const long mbase = (long)sidx * (O_ * T_) + (long)u * m1;

    float* s_q = sm;                        // N*16
    float* s_v = s_q + N * HD_;             // N*16
    float* s_p = s_v + N * HD_;             // N*PSTR
    int*   s_m = (int*)(s_p + N * PSTR);    // N

    const float* qb = qkv + (long)bl * N * 384;

    // Phase A: stage q, V (float4 granules) and mask
    for (int idx = tid; idx < N * 4; idx += 256) {
        int n = idx >> 2, t = idx & 3;
        *(float4*)(s_q + n * HD_ + t * 4) = *(const float4*)(qb + (long)n * 384 + h * HD_ + t * 4);
        *(float4*)(s_v + n * HD_ + t * 4) = *(const float4*)(qb + (long)n * 384 + 256 + h * HD_ + t * 4);
    }
    for (int idx = tid; idx < N; idx += 256)
        s_m[idx] = (mask[mbase + (long)idx * m2] != 0);

    // K per-lane registers
    const int j1 = lane, j2 = lane + 64;
    const bool has2 = (j2 < N);
    float kr1[HD_], kr2[HD_];
    {
        const float4* kb = (const float4*)(qb + (long)j1 * 384 + 128 + h * HD_);
        #pragma unroll
        for (int t = 0; t < 4; ++t) {
            float4 f = kb[t];
            kr1[t * 4] = f.x; kr1[t * 4 + 1] = f.y; kr1[t * 4 + 2] = f.z; kr1[t * 4 + 3] = f.w;
        }
        #pragma unroll
        for (int t = 0; t < HD_; ++t) kr2[t] = 0.f;
        if (has2) {
            const float4* kb2 = (const float4*)(qb + (long)j2 * 384 + 128 + h * HD_);
            #pragma unroll
            for (int t = 0; t < 4; ++t) {
                float4 f = kb2[t];
                kr2[t * 4] = f.x; kr2[t * 4 + 1] = f.y; kr2[t * 4 + 2] = f.z; kr2[t * 4 + 3] = f.w;
            }
        }
    }
    __syncthreads();
    const int mj1 = s_m[j1];
    const int mj2 = has2 ? s_m[j2] : 0;

    // Phase B: scores + softmax (no max-subtract), rows striped across waves
    for (int i = w; i < N; i += 4) {
        const float4* qp = (const float4*)(s_q + i * HD_);
        float qv[HD_];
        #pragma unroll
        for (int t = 0; t < 4; ++t) {
            float4 f = qp[t];
            qv[t * 4] = f.x; qv[t * 4 + 1] = f.y; qv[t * 4 + 2] = f.z; qv[t * 4 + 3] = f.w;
        }
        float d1 = 0.f, d2 = 0.f;
        #pragma unroll
        for (int d = 0; d < HD_; ++d) d1 += qv[d] * kr1[d];
        if (N > 64) {
            #pragma unroll
            for (int d = 0; d < HD_; ++d) d2 += qv[d] * kr2[d];
        }
        const int mi = s_m[i];
        // dead row (mi==0): all scores 0 -> uniform softmax over all N
        float a1 = mi ? (mj1 ? d1 * 0.25f : -1e30f) : 0.f;
        float a2 = mi ? (mj2 ? d2 * 0.25f : -1e30f) : 0.f;
        float e1 = __expf(a1);
        float e2 = has2 ? __expf(a2) : 0.f;
        float ss = e1 + e2;
        #pragma unroll
        for (int off = 32; off; off >>= 1) ss += __shfl_xor(ss, off, 64);
        float inv = 1.f / ss;
        s_p[i * PSTR + j1] = e1 * inv;
        if (has2) s_p[i * PSTR + j2] = e2 * inv;
    }
    __syncthreads();

    // Phase C: PV, register-blocked 2 rows x 4 cols per thread
    const int rg = tid >> 2, cg = tid & 3;
    const bool r2ok = (rg + 64) < N;
    const float* pr1 = s_p + rg * PSTR;
    const float* pr2 = pr1 + 64 * PSTR;
    const float* vb = s_v + cg * 4;
    float acc[8] = {};
    int j = 0;
    #pragma unroll 2
    for (; j + 2 <= N; j += 2) {
        float2 pa = *(const float2*)(pr1 + j);
        float4 v0 = *(const float4*)(vb + j * HD_);
        float4 v1 = *(const float4*)(vb + (j + 1) * HD_);
        acc[0] += pa.x * v0.x + pa.y * v1.x;
        acc[1] += pa.x * v0.y + pa.y * v1.y;
        acc[2] += pa.x * v0.z + pa.y * v1.z;
        acc[3] += pa.x * v0.w + pa.y * v1.w;
        if (r2ok) {
            float2 pb = *(const float2*)(pr2 + j);
            acc[4] += pb.x * v0.x + pb.y * v1.x;
            acc[5] += pb.x * v0.y + pb.y * v1.y;
            acc[6] += pb.x * v0.z + pb.y * v1.z;
            acc[7] += pb.x * v0.w + pb.y * v1.w;
        }
    }
    if (j < N) {
        float pa = pr1[j];
        float4 v0 = *(const float4*)(vb + j * HD_);
        acc[0] += pa * v0.x; acc[1] += pa * v0.y; acc[2] += pa * v0.z; acc[3] += pa * v0.w;
        if (r2ok) {
            float pb = pr2[j];
            acc[4] += pb * v0.x; acc[5] += pb * v0.y; acc[6] += pb * v0.z; acc[7] += pb * v0.w;
        }
    }
    {
        float4 o1; o1.x = acc[0]; o1.y = acc[1]; o1.z = acc[2]; o1.w = acc[3];
        *(float4*)(y + ((long)bl * N + rg) * C_ + h * HD_ + cg * 4) = o1;
        if (r2ok) {
            float4 o2; o2.x = acc[4]; o2.y = acc[5]; o2.z = acc[6]; o2.w = acc[7];
            *(float4*)(y + ((long)bl * N + rg + 64) * C_ + h * HD_ + cg * 4) = o2;
        }
    }
}

extern "C" void kernel_launch(void* const* d_in, const int* in_sizes, int n_in,
                              void* d_out, int out_size, void* d_ws, size_t ws_size,
                              hipStream_t stream) {
    const float* x       = (const float*)d_in[0];
    const int*   mask    = (const int*)d_in[1];
    const float* Wqkv_a  = (const float*)d_in[2];
    const float* Wproj_a = (const float*)d_in[3];
    const float* bproj_a = (const float*)d_in[4];
    const float* Wqkv_t  = (const float*)d_in[5];
    const float* Wproj_t = (const float*)d_in[6];
    const float* bproj_t = (const float*)d_in[7];
    float* out   = (float*)d_out;
    float* qkvws = (float*)d_ws;   // 46592*384*4 = 71.6 MB (reused per chunk)

    const dim3 gq(ROWS_CHUNK / 64, 3);
    const dim3 gp(ROWS_CHUNK / 64, 1);
    const size_t lds1 = (size_t)(O_ * HD_ * 2 + O_ * PSTR + O_) * 4;   // 32.0 KB
    const size_t lds2 = (size_t)(T_ * HD_ * 2 + T_ * PSTR + T_) * 4;   // 45.5 KB

    // ---- Pass 1: agent attention (tokens = objects, N=64), row order (s,t,o)
    for (int c = 0; c < NCHUNK; ++c) {
        const int rowbase = c * ROWS_CHUNK;
        gemm_rows<<<gq, 256, 0, stream>>>(x, Wqkv_a, nullptr, qkvws,
            rowbase, 3 * C_,
            T_ * O_, (long)O_ * T_ * C_,
            O_, T_, (long)C_,
            O_, (long)T_ * C_);
        dim3 ga(SC_ * T_, H_);
        attn_kernel<<<ga, 256, lds1, stream>>>(qkvws, mask, out + (long)rowbase * C_,
            O_, c * SC_ * T_, T_, 1L, (long)T_);
        gemm_rows<<<gp, 256, 0, stream>>>(out + (long)rowbase * C_, Wproj_a, bproj_a,
            out + (long)rowbase * C_,
            0, C_, 1, (long)C_, 1, 1, 0L, 1, 0L);
    }

    // ---- Pass 2: time attention (tokens = timesteps, N=91), row order (s,o,t)
    for (int c = 0; c < NCHUNK; ++c) {
        const int rowbase = c * ROWS_CHUNK;
        gemm_rows<<<gq, 256, 0, stream>>>(out, Wqkv_t, nullptr, qkvws,
            rowbase, 3 * C_,
            O_ * T_, (long)T_ * O_ * C_,
            T_, O_, (long)C_,
            T_, (long)O_ * C_);
        dim3 ga(SC_ * O_, H_);
        attn_kernel<<<ga, 256, lds2, stream>>>(qkvws, mask, out + (long)rowbase * C_,
            T_, c * SC_ * O_, O_, (long)T_, 1L);
        gemm_rows<<<gp, 256, 0, stream>>>(out + (long)rowbase * C_, Wproj_t, bproj_t,
            out + (long)rowbase * C_,
            0, C_, 1, (long)C_, 1, 1, 0L, 1, 0L);
    }
}

// Round 4
// 1162.318 us; speedup vs baseline: 8.0047x; 1.4920x over previous
//
#include <hip/hip_runtime.h>

#define S_ 32
#define O_ 64
#define T_ 91
#define C_ 128
#define H_ 8
#define HD_ 16
#define NCHUNK 4
#define SC_ (S_ / NCHUNK)             // 8 scenes per chunk
#define ROWS_CHUNK (SC_ * O_ * T_)    // 46592 tokens per chunk
#define PSTR 92                       // attn s_p row stride

typedef __attribute__((ext_vector_type(8))) short short8;
typedef __attribute__((ext_vector_type(4))) float f32x4;

// ---------------------------------------------------------------------------
// Weight prep: W (NC x 128 fp32, row-major) -> hi/lo bf16 (as shorts) in
// MFMA-fragment-linear order. Element (c,k):
//   ct=c>>4, cl=c&15, kp=k>>5, g=(k>>3)&3, j=k&7
//   idx = ct*2048 + kp*512 + (cl+16*g)*8 + j
// hi = truncate-to-bf16(w), lo = truncate-to-bf16(w - hi). Missing mass
// <= ~3*2^-16 |w| -> negligible.
// ---------------------------------------------------------------------------
__global__ __launch_bounds__(256) void prep_w(const float* __restrict__ W,
                                              short* __restrict__ hi,
                                              short* __restrict__ lo, int NC)
{
    int t = blockIdx.x * 256 + threadIdx.x;
    if (t >= NC * 16) return;
    int c = t >> 4, gk = t & 15;          // gk = k/8
    int kp = gk >> 2, g = gk & 3;
    int ct = c >> 4, cl = c & 15;
    const float* src = W + (long)c * C_ + gk * 8;
    long slot = (long)ct * 2048 + kp * 512 + (cl + 16 * g) * 8;
    short8 vh, vl;
    #pragma unroll
    for (int j = 0; j < 8; ++j) {
        float f = src[j];
        unsigned u = __float_as_uint(f);
        float hf = __uint_as_float(u & 0xffff0000u);
        vh[j] = (short)(u >> 16);
        vl[j] = (short)(__float_as_uint(f - hf) >> 16);
    }
    *(short8*)(hi + slot) = vh;
    *(short8*)(lo + slot) = vl;
}

// ---------------------------------------------------------------------------
// Split-bf16 MFMA GEMM: out[lr][c] = dot(A_row(R), W[c]) (+ bias[c])
//   R = row0 + lr, gather off(R) = (R/DA)*s1 + ((R/DB)%MB)*s2 + (R%MC)*s3
// Block: 64 rows x 128 cols, 4 waves; wave w owns rows [w*16, w*16+16).
// No LDS. A loaded per-lane in fragment layout (lane row = l&15,
// k = (l>>4)*8 + j), converted to bf16 hi/lo in regs. B frags from
// pre-converted frag-linear buffers (lane-contiguous 16B loads).
// 3 MFMAs per (ct,kp): AhBh + AlBh + AhBl. In-place safe (out==A, identity
// gather, gridDim.y==1): wave's loads feed its MFMAs before epilogue stores.
// ---------------------------------------------------------------------------
__global__ __launch_bounds__(256) void gemm_mfma(
    const float* __restrict__ A, const short* __restrict__ Whi,
    const short* __restrict__ Wlo, const float* __restrict__ bias,
    float* __restrict__ out, int row0, int ncols,
    int DA, long s1, int DB, int MB, long s2, int MC, long s3)
{
    const int tid = threadIdx.x;
    const int w = tid >> 6, l = tid & 63;
    const int rl = l & 15, g = l >> 4;
    const int lr0 = blockIdx.x * 64 + w * 16;
    const int R = row0 + lr0 + rl;
    const long aoff = (long)(R / DA) * s1 + (long)((R / DB) % MB) * s2 + (long)(R % MC) * s3;
    const float* arow = A + aoff + g * 8;
    const int c0 = blockIdx.y * 128;
    const long bbase = (long)(c0 >> 4) * 2048 + (long)l * 8;
    const short* bhp = Whi + bbase;
    const short* blp = Wlo + bbase;

    f32x4 acc[8];
    #pragma unroll
    for (int i = 0; i < 8; ++i) acc[i] = (f32x4){0.f, 0.f, 0.f, 0.f};

    #pragma unroll
    for (int kp = 0; kp < 4; ++kp) {
        float4 a0 = *(const float4*)(arow + kp * 32);
        float4 a1 = *(const float4*)(arow + kp * 32 + 4);
        float av[8] = {a0.x, a0.y, a0.z, a0.w, a1.x, a1.y, a1.z, a1.w};
        short8 ah, al;
        #pragma unroll
        for (int j = 0; j < 8; ++j) {
            unsigned u = __float_as_uint(av[j]);
            float hf = __uint_as_float(u & 0xffff0000u);
            ah[j] = (short)(u >> 16);
            al[j] = (short)(__float_as_uint(av[j] - hf) >> 16);
        }
        #pragma unroll
        for (int ct = 0; ct < 8; ++ct) {
            short8 b0 = *(const short8*)(bhp + ct * 2048 + kp * 512);
            short8 b1 = *(const short8*)(blp + ct * 2048 + kp * 512);
            acc[ct] = __builtin_amdgcn_mfma_f32_16x16x32_bf16(ah, b0, acc[ct], 0, 0, 0);
            acc[ct] = __builtin_amdgcn_mfma_f32_16x16x32_bf16(al, b0, acc[ct], 0, 0, 0);
            acc[ct] = __builtin_amdgcn_mfma_f32_16x16x32_bf16(ah, b1, acc[ct], 0, 0, 0);
        }
    }

    // Epilogue: D frag layout col=l&15, row=(l>>4)*4+r
    #pragma unroll
    for (int ct = 0; ct < 8; ++ct) {
        int cc = c0 + ct * 16 + rl;
        float bv = bias ? bias[cc] : 0.f;
        #pragma unroll
        for (int r = 0; r < 4; ++r)
            out[(long)(lr0 + g * 4 + r) * ncols + cc] = acc[ct][r] + bv;
    }
}

// ---------------------------------------------------------------------------
// Attention core (unchanged from round 3): K in per-lane regs, q/V in LDS,
// softmax without max-subtract, PV register-blocked.
// ---------------------------------------------------------------------------
__global__ __launch_bounds__(256) void attn_kernel(
    const float* __restrict__ qkv, const int* __restrict__ mask,
    float* __restrict__ y, int N, int b0, int bdiv, long m1, long m2)
{
    extern __shared__ float sm[];
    const int bl = blockIdx.x, h = blockIdx.y;
    const int tid = threadIdx.x, lane = tid & 63, w = tid >> 6;
    const int b = b0 + bl;
    const int sidx = b / bdiv, u = b - sidx * bdiv;
    const long mbase = (long)sidx * (O_ * T_) + (long)u * m1;

    float* s_q = sm;                        // N*16
    float* s_v = s_q + N * HD_;             // N*16
    float* s_p = s_v + N * HD_;             // N*PSTR
    int*   s_m = (int*)(s_p + N * PSTR);    // N

    const float* qb = qkv + (long)bl * N * 384;

    for (int idx = tid; idx < N * 4; idx += 256) {
        int n = idx >> 2, t = idx & 3;
        *(float4*)(s_q + n * HD_ + t * 4) = *(const float4*)(qb + (long)n * 384 + h * HD_ + t * 4);
        *(float4*)(s_v + n * HD_ + t * 4) = *(const float4*)(qb + (long)n * 384 + 256 + h * HD_ + t * 4);
    }
    for (int idx = tid; idx < N; idx += 256)
        s_m[idx] = (mask[mbase + (long)idx * m2] != 0);

    const int j1 = lane, j2 = lane + 64;
    const bool has2 = (j2 < N);
    float kr1[HD_], kr2[HD_];
    {
        const float4* kb = (const float4*)(qb + (long)j1 * 384 + 128 + h * HD_);
        #pragma unroll
        for (int t = 0; t < 4; ++t) {
            float4 f = kb[t];
            kr1[t * 4] = f.x; kr1[t * 4 + 1] = f.y; kr1[t * 4 + 2] = f.z; kr1[t * 4 + 3] = f.w;
        }
        #pragma unroll
        for (int t = 0; t < HD_; ++t) kr2[t] = 0.f;
        if (has2) {
            const float4* kb2 = (const float4*)(qb + (long)j2 * 384 + 128 + h * HD_);
            #pragma unroll
            for (int t = 0; t < 4; ++t) {
                float4 f = kb2[t];
                kr2[t * 4] = f.x; kr2[t * 4 + 1] = f.y; kr2[t * 4 + 2] = f.z; kr2[t * 4 + 3] = f.w;
            }
        }
    }
    __syncthreads();
    const int mj1 = s_m[j1];
    const int mj2 = has2 ? s_m[j2] : 0;

    for (int i = w; i < N; i += 4) {
        const float4* qp = (const float4*)(s_q + i * HD_);
        float qv[HD_];
        #pragma unroll
        for (int t = 0; t < 4; ++t) {
            float4 f = qp[t];
            qv[t * 4] = f.x; qv[t * 4 + 1] = f.y; qv[t * 4 + 2] = f.z; qv[t * 4 + 3] = f.w;
        }
        float d1 = 0.f, d2 = 0.f;
        #pragma unroll
        for (int d = 0; d < HD_; ++d) d1 += qv[d] * kr1[d];
        if (N > 64) {
            #pragma unroll
            for (int d = 0; d < HD_; ++d) d2 += qv[d] * kr2[d];
        }
        const int mi = s_m[i];
        float a1 = mi ? (mj1 ? d1 * 0.25f : -1e30f) : 0.f;
        float a2 = mi ? (mj2 ? d2 * 0.25f : -1e30f) : 0.f;
        float e1 = __expf(a1);
        float e2 = has2 ? __expf(a2) : 0.f;
        float ss = e1 + e2;
        #pragma unroll
        for (int off = 32; off; off >>= 1) ss += __shfl_xor(ss, off, 64);
        float inv = 1.f / ss;
        s_p[i * PSTR + j1] = e1 * inv;
        if (has2) s_p[i * PSTR + j2] = e2 * inv;
    }
    __syncthreads();

    const int rg = tid >> 2, cg = tid & 3;
    const bool r2ok = (rg + 64) < N;
    const float* pr1 = s_p + rg * PSTR;
    const float* pr2 = pr1 + 64 * PSTR;
    const float* vb = s_v + cg * 4;
    float acc[8] = {};
    int j = 0;
    #pragma unroll 2
    for (; j + 2 <= N; j += 2) {
        float2 pa = *(const float2*)(pr1 + j);
        float4 v0 = *(const float4*)(vb + j * HD_);
        float4 v1 = *(const float4*)(vb + (j + 1) * HD_);
        acc[0] += pa.x * v0.x + pa.y * v1.x;
        acc[1] += pa.x * v0.y + pa.y * v1.y;
        acc[2] += pa.x * v0.z + pa.y * v1.z;
        acc[3] += pa.x * v0.w + pa.y * v1.w;
        if (r2ok) {
            float2 pb = *(const float2*)(pr2 + j);
            acc[4] += pb.x * v0.x + pb.y * v1.x;
            acc[5] += pb.x * v0.y + pb.y * v1.y;
            acc[6] += pb.x * v0.z + pb.y * v1.z;
            acc[7] += pb.x * v0.w + pb.y * v1.w;
        }
    }
    if (j < N) {
        float pa = pr1[j];
        float4 v0 = *(const float4*)(vb + j * HD_);
        acc[0] += pa * v0.x; acc[1] += pa * v0.y; acc[2] += pa * v0.z; acc[3] += pa * v0.w;
        if (r2ok) {
            float pb = pr2[j];
            acc[4] += pb * v0.x; acc[5] += pb * v0.y; acc[6] += pb * v0.z; acc[7] += pb * v0.w;
        }
    }
    {
        float4 o1; o1.x = acc[0]; o1.y = acc[1]; o1.z = acc[2]; o1.w = acc[3];
        *(float4*)(y + ((long)bl * N + rg) * C_ + h * HD_ + cg * 4) = o1;
        if (r2ok) {
            float4 o2; o2.x = acc[4]; o2.y = acc[5]; o2.z = acc[6]; o2.w = acc[7];
            *(float4*)(y + ((long)bl * N + rg + 64) * C_ + h * HD_ + cg * 4) = o2;
        }
    }
}

extern "C" void kernel_launch(void* const* d_in, const int* in_sizes, int n_in,
                              void* d_out, int out_size, void* d_ws, size_t ws_size,
                              hipStream_t stream) {
    const float* x       = (const float*)d_in[0];
    const int*   mask    = (const int*)d_in[1];
    const float* Wqkv_a  = (const float*)d_in[2];
    const float* Wproj_a = (const float*)d_in[3];
    const float* bproj_a = (const float*)d_in[4];
    const float* Wqkv_t  = (const float*)d_in[5];
    const float* Wproj_t = (const float*)d_in[6];
    const float* bproj_t = (const float*)d_in[7];
    float* out   = (float*)d_out;
    float* qkvws = (float*)d_ws;                       // 71.6 MB A/qkv scratch (per chunk)

    // Converted weights live after the qkv buffer (~512 KB)
    short* wb = (short*)(qkvws + (size_t)ROWS_CHUNK * 384);
    const int WQ = 384 * C_;   // 49152 shorts per part
    const int WP = C_ * C_;    // 16384 shorts per part
    short* wqa_h = wb;              short* wqa_l = wqa_h + WQ;
    short* wqt_h = wqa_l + WQ;      short* wqt_l = wqt_h + WQ;
    short* wpa_h = wqt_l + WQ;      short* wpa_l = wpa_h + WP;
    short* wpt_h = wpa_l + WP;      short* wpt_l = wpt_h + WP;

    prep_w<<<(384 * 16 + 255) / 256, 256, 0, stream>>>(Wqkv_a, wqa_h, wqa_l, 384);
    prep_w<<<(384 * 16 + 255) / 256, 256, 0, stream>>>(Wqkv_t, wqt_h, wqt_l, 384);
    prep_w<<<(128 * 16 + 255) / 256, 256, 0, stream>>>(Wproj_a, wpa_h, wpa_l, 128);
    prep_w<<<(128 * 16 + 255) / 256, 256, 0, stream>>>(Wproj_t, wpt_h, wpt_l, 128);

    const dim3 gq(ROWS_CHUNK / 64, 3);
    const dim3 gp(ROWS_CHUNK / 64, 1);
    const size_t lds1 = (size_t)(O_ * HD_ * 2 + O_ * PSTR + O_) * 4;   // 32.0 KB
    const size_t lds2 = (size_t)(T_ * HD_ * 2 + T_ * PSTR + T_) * 4;   // 45.5 KB

    // ---- Pass 1: agent attention (tokens = objects, N=64), row order (s,t,o)
    for (int c = 0; c < NCHUNK; ++c) {
        const int rowbase = c * ROWS_CHUNK;
        gemm_mfma<<<gq, 256, 0, stream>>>(x, wqa_h, wqa_l, nullptr, qkvws,
            rowbase, 3 * C_,
            T_ * O_, (long)O_ * T_ * C_,
            O_, T_, (long)C_,
            O_, (long)T_ * C_);
        dim3 ga(SC_ * T_, H_);
        attn_kernel<<<ga, 256, lds1, stream>>>(qkvws, mask, out + (long)rowbase * C_,
            O_, c * SC_ * T_, T_, 1L, (long)T_);
        gemm_mfma<<<gp, 256, 0, stream>>>(out + (long)rowbase * C_, wpa_h, wpa_l, bproj_a,
            out + (long)rowbase * C_,
            0, C_, 1, (long)C_, 1, 1, 0L, 1, 0L);
    }

    // ---- Pass 2: time attention (tokens = timesteps, N=91), row order (s,o,t)
    for (int c = 0; c < NCHUNK; ++c) {
        const int rowbase = c * ROWS_CHUNK;
        gemm_mfma<<<gq, 256, 0, stream>>>(out, wqt_h, wqt_l, nullptr, qkvws,
            rowbase, 3 * C_,
            O_ * T_, (long)T_ * O_ * C_,
            T_, O_, (long)C_,
            T_, (long)O_ * C_);
        dim3 ga(SC_ * O_, H_);
        attn_kernel<<<ga, 256, lds2, stream>>>(qkvws, mask, out + (long)rowbase * C_,
            T_, c * SC_ * O_, O_, (long)T_, 1L);
        gemm_mfma<<<gp, 256, 0, stream>>>(out + (long)rowbase * C_, wpt_h, wpt_l, bproj_t,
            out + (long)rowbase * C_,
            0, C_, 1, (long)C_, 1, 1, 0L, 1, 0L);
    }
}

// Round 5
// 746.381 us; speedup vs baseline: 12.4655x; 1.5573x over previous
//
#include <hip/hip_runtime.h>

#define S_ 32
#define O_ 64
#define T_ 91
#define C_ 128
#define H_ 8
#define HD_ 16
#define NCHUNK 4
#define SC_ (S_ / NCHUNK)             // 8 scenes per chunk
#define ROWS_CHUNK (SC_ * O_ * T_)    // 46592 tokens per chunk

typedef __attribute__((ext_vector_type(8))) short short8;
typedef __attribute__((ext_vector_type(4))) short short4b;
typedef __attribute__((ext_vector_type(4))) float f32x4;

// ---------------------------------------------------------------------------
// Weight prep: W (NC x 128 fp32) -> hi/lo bf16 in 16x16x32 B-frag-linear order
// (for the GEMM kernels). idx = ct*2048 + kp*512 + (cl+16*g)*8 + j.
// ---------------------------------------------------------------------------
__global__ __launch_bounds__(256) void prep_w(const float* __restrict__ W,
                                              short* __restrict__ hi,
                                              short* __restrict__ lo, int NC)
{
    int t = blockIdx.x * 256 + threadIdx.x;
    if (t >= NC * 16) return;
    int c = t >> 4, gk = t & 15;
    int kp = gk >> 2, g = gk & 3;
    int ct = c >> 4, cl = c & 15;
    const float* src = W + (long)c * C_ + gk * 8;
    long slot = (long)ct * 2048 + kp * 512 + (cl + 16 * g) * 8;
    short8 vh, vl;
    #pragma unroll
    for (int j = 0; j < 8; ++j) {
        float f = src[j];
        unsigned u = __float_as_uint(f);
        float hf = __uint_as_float(u & 0xffff0000u);
        vh[j] = (short)(u >> 16);
        vl[j] = (short)(__float_as_uint(f - hf) >> 16);
    }
    *(short8*)(hi + slot) = vh;
    *(short8*)(lo + slot) = vl;
}

// ---------------------------------------------------------------------------
// Split-bf16 MFMA GEMM (16x16x32). mode 0: f32 out (+bias). mode 1: split
// hi/lo bf16 (truncate) to outh/outl. In-place safe for mode 0 (out==A,
// identity gather, gridDim.y==1).
// ---------------------------------------------------------------------------
__global__ __launch_bounds__(256) void gemm_mfma(
    const float* __restrict__ A, const short* __restrict__ Whi,
    const short* __restrict__ Wlo, const float* __restrict__ bias,
    float* __restrict__ out, unsigned short* __restrict__ outh,
    unsigned short* __restrict__ outl, int mode, int row0, int ncols,
    int DA, long s1, int DB, int MB, long s2, int MC, long s3)
{
    const int tid = threadIdx.x;
    const int w = tid >> 6, l = tid & 63;
    const int rl = l & 15, g = l >> 4;
    const int lr0 = blockIdx.x * 64 + w * 16;
    const int R = row0 + lr0 + rl;
    const long aoff = (long)(R / DA) * s1 + (long)((R / DB) % MB) * s2 + (long)(R % MC) * s3;
    const float* arow = A + aoff + g * 8;
    const int c0 = blockIdx.y * 128;
    const long bbase = (long)(c0 >> 4) * 2048 + (long)l * 8;
    const short* bhp = Whi + bbase;
    const short* blp = Wlo + bbase;

    f32x4 acc[8];
    #pragma unroll
    for (int i = 0; i < 8; ++i) acc[i] = (f32x4){0.f, 0.f, 0.f, 0.f};

    #pragma unroll
    for (int kp = 0; kp < 4; ++kp) {
        float4 a0 = *(const float4*)(arow + kp * 32);
        float4 a1 = *(const float4*)(arow + kp * 32 + 4);
        float av[8] = {a0.x, a0.y, a0.z, a0.w, a1.x, a1.y, a1.z, a1.w};
        short8 ah, al;
        #pragma unroll
        for (int j = 0; j < 8; ++j) {
            unsigned u = __float_as_uint(av[j]);
            float hf = __uint_as_float(u & 0xffff0000u);
            ah[j] = (short)(u >> 16);
            al[j] = (short)(__float_as_uint(av[j] - hf) >> 16);
        }
        #pragma unroll
        for (int ct = 0; ct < 8; ++ct) {
            short8 b0 = *(const short8*)(bhp + ct * 2048 + kp * 512);
            short8 b1 = *(const short8*)(blp + ct * 2048 + kp * 512);
            acc[ct] = __builtin_amdgcn_mfma_f32_16x16x32_bf16(ah, b0, acc[ct], 0, 0, 0);
            acc[ct] = __builtin_amdgcn_mfma_f32_16x16x32_bf16(al, b0, acc[ct], 0, 0, 0);
            acc[ct] = __builtin_amdgcn_mfma_f32_16x16x32_bf16(ah, b1, acc[ct], 0, 0, 0);
        }
    }

    #pragma unroll
    for (int ct = 0; ct < 8; ++ct) {
        int cc = c0 + ct * 16 + rl;
        if (mode == 0) {
            float bv = bias ? bias[cc] : 0.f;
            #pragma unroll
            for (int r = 0; r < 4; ++r)
                out[(long)(lr0 + g * 4 + r) * ncols + cc] = acc[ct][r] + bv;
        } else {
            #pragma unroll
            for (int r = 0; r < 4; ++r) {
                long row = lr0 + g * 4 + r;
                float v = acc[ct][r];
                unsigned u = __float_as_uint(v);
                float hf = __uint_as_float(u & 0xffff0000u);
                outh[row * ncols + cc] = (unsigned short)(u >> 16);
                outl[row * ncols + cc] = (unsigned short)(__float_as_uint(v - hf) >> 16);
            }
        }
    }
}

// ---------------------------------------------------------------------------
// MFMA attention: one wave per (batch, head). qkv in split bf16 (qh/ql),
// chunk-local rows [bl*N + n][384]. Swapped S^T = mfma(K, Q) so e-values land
// in PV's A-frag layout (lane = query col l&15, k = key (l>>4)*4+r). 3-term
// split MFMAs throughout. Softmax: no max-sub, sum via 2 shfl_xor, deferred
// normalization via ds_bpermute of 1/sum. Dead row -> e=1 over j<N.
// ---------------------------------------------------------------------------
template<int N, int NT>
__global__ __launch_bounds__(256) void attn_mfma(
    const unsigned short* __restrict__ qh, const unsigned short* __restrict__ ql,
    const int* __restrict__ mask, float* __restrict__ y,
    int b0, int bdiv, long m1, long m2)
{
    __shared__ int s_m[NT * 16];
    const int tid = threadIdx.x;
    const int wv = tid >> 6, l = tid & 63;
    const int g = l >> 4, ic = l & 15;
    const int bl = blockIdx.x;
    const int h = blockIdx.y * 4 + wv;
    const int b = b0 + bl;
    const int sidx = b / bdiv, u = b - sidx * bdiv;
    const long mbase = (long)sidx * (O_ * T_) + (long)u * m1;

    for (int idx = tid; idx < NT * 16; idx += 256)
        s_m[idx] = (idx < N) ? (mask[mbase + (long)idx * m2] != 0) : 0;
    __syncthreads();

    const long rowbase = (long)bl * N;

    // K A-frags: row j = 16jt + ic (clamped), k = d = 4g + rk
    short4b kh[NT], kl[NT];
    #pragma unroll
    for (int jt = 0; jt < NT; ++jt) {
        int j = jt * 16 + ic; if (j >= N) j = N - 1;
        long off = (rowbase + j) * 384 + 128 + h * HD_ + g * 4;
        kh[jt] = *(const short4b*)(qh + off);
        kl[jt] = *(const short4b*)(ql + off);
    }
    // V B-frags: col c = ic, k = j = 16kt + 4g + rk (clamped; masked by e=0)
    short4b vh[NT], vl[NT];
    #pragma unroll
    for (int kt = 0; kt < NT; ++kt) {
        #pragma unroll
        for (int rk = 0; rk < 4; ++rk) {
            int j = kt * 16 + g * 4 + rk; if (j >= N) j = N - 1;
            long off = (rowbase + j) * 384 + 256 + h * HD_ + ic;
            vh[kt][rk] = (short)qh[off];
            vl[kt][rk] = (short)ql[off];
        }
    }
    // per-lane key bitmasks over (jt, r): j = 16jt + 4g + r
    unsigned mbits = 0, jbits = 0;
    #pragma unroll
    for (int jt = 0; jt < NT; ++jt)
        #pragma unroll
        for (int r = 0; r < 4; ++r) {
            int j = jt * 16 + 4 * g + r;
            if (j < N) {
                jbits |= 1u << (jt * 4 + r);
                if (s_m[j]) mbits |= 1u << (jt * 4 + r);
            }
        }

    for (int it = 0; it < NT; ++it) {
        // Q B-frag: col i = 16it + ic, k = d = 4g + rk
        const int iq = it * 16 + ic;
        const bool iok = iq < N;
        const int iqc = iok ? iq : N - 1;
        const long qoff = (rowbase + iqc) * 384 + h * HD_ + g * 4;
        short4b qhf = *(const short4b*)(qh + qoff);
        short4b qlf = *(const short4b*)(ql + qoff);
        const int qm = s_m[iqc];

        f32x4 sa[NT];
        #pragma unroll
        for (int jt = 0; jt < NT; ++jt) sa[jt] = (f32x4){0.f, 0.f, 0.f, 0.f};
        #pragma unroll
        for (int jt = 0; jt < NT; ++jt) {
            sa[jt] = __builtin_amdgcn_mfma_f32_16x16x16bf16_1k(kh[jt], qhf, sa[jt], 0, 0, 0);
            sa[jt] = __builtin_amdgcn_mfma_f32_16x16x16bf16_1k(kl[jt], qhf, sa[jt], 0, 0, 0);
            sa[jt] = __builtin_amdgcn_mfma_f32_16x16x16bf16_1k(kh[jt], qlf, sa[jt], 0, 0, 0);
        }

        // e = softmax numerator (unnormalized), packed into PV A-frags
        float sum = 0.f;
        short4b ph[NT], pl[NT];
        #pragma unroll
        for (int jt = 0; jt < NT; ++jt) {
            #pragma unroll
            for (int r = 0; r < 4; ++r) {
                int bit = (jt << 2) + r;
                float e;
                if (!iok) e = 0.f;
                else if (!qm) e = ((jbits >> bit) & 1) ? 1.f : 0.f;
                else e = ((mbits >> bit) & 1) ? __expf(sa[jt][r] * 0.25f) : 0.f;
                sum += e;
                unsigned ue = __float_as_uint(e);
                float ehf = __uint_as_float(ue & 0xffff0000u);
                ph[jt][r] = (short)(ue >> 16);
                pl[jt][r] = (short)(__float_as_uint(e - ehf) >> 16);
            }
        }
        sum += __shfl_xor(sum, 16, 64);
        sum += __shfl_xor(sum, 32, 64);
        const float inv = 1.f / sum;

        // PV: out[i][c], 3-term split
        f32x4 pv = (f32x4){0.f, 0.f, 0.f, 0.f};
        #pragma unroll
        for (int kt = 0; kt < NT; ++kt) {
            pv = __builtin_amdgcn_mfma_f32_16x16x16bf16_1k(ph[kt], vh[kt], pv, 0, 0, 0);
            pv = __builtin_amdgcn_mfma_f32_16x16x16bf16_1k(pl[kt], vh[kt], pv, 0, 0, 0);
            pv = __builtin_amdgcn_mfma_f32_16x16x16bf16_1k(ph[kt], vl[kt], pv, 0, 0, 0);
        }

        // store rows 16it + 4g + r (scaled by that row's inv, fetched cross-lane)
        #pragma unroll
        for (int r = 0; r < 4; ++r) {
            int rloc = 4 * g + r;
            int row = it * 16 + rloc;
            int iv = __builtin_amdgcn_ds_bpermute(rloc << 2, __float_as_int(inv));
            if (row < N)
                y[(rowbase + row) * C_ + h * HD_ + ic] = pv[r] * __int_as_float(iv);
        }
    }
}

extern "C" void kernel_launch(void* const* d_in, const int* in_sizes, int n_in,
                              void* d_out, int out_size, void* d_ws, size_t ws_size,
                              hipStream_t stream) {
    const float* x       = (const float*)d_in[0];
    const int*   mask    = (const int*)d_in[1];
    const float* Wqkv_a  = (const float*)d_in[2];
    const float* Wproj_a = (const float*)d_in[3];
    const float* bproj_a = (const float*)d_in[4];
    const float* Wqkv_t  = (const float*)d_in[5];
    const float* Wproj_t = (const float*)d_in[6];
    const float* bproj_t = (const float*)d_in[7];
    float* out = (float*)d_out;

    // d_ws layout: qkv_h | qkv_l (split bf16 qkv, chunk-local) | prepped weights
    unsigned short* qkv_h = (unsigned short*)d_ws;                 // 35.78 MB
    unsigned short* qkv_l = qkv_h + (size_t)ROWS_CHUNK * 384;      // 35.78 MB
    short* wb = (short*)(qkv_l + (size_t)ROWS_CHUNK * 384);        // 0.5 MB
    const int WQ = 384 * C_;
    const int WP = C_ * C_;
    short* wqa_h = wb;              short* wqa_l = wqa_h + WQ;
    short* wqt_h = wqa_l + WQ;      short* wqt_l = wqt_h + WQ;
    short* wpa_h = wqt_l + WQ;      short* wpa_l = wpa_h + WP;
    short* wpt_h = wpa_l + WP;      short* wpt_l = wpt_h + WP;

    prep_w<<<(384 * 16 + 255) / 256, 256, 0, stream>>>(Wqkv_a, wqa_h, wqa_l, 384);
    prep_w<<<(384 * 16 + 255) / 256, 256, 0, stream>>>(Wqkv_t, wqt_h, wqt_l, 384);
    prep_w<<<(128 * 16 + 255) / 256, 256, 0, stream>>>(Wproj_a, wpa_h, wpa_l, 128);
    prep_w<<<(128 * 16 + 255) / 256, 256, 0, stream>>>(Wproj_t, wpt_h, wpt_l, 128);

    const dim3 gq(ROWS_CHUNK / 64, 3);
    const dim3 gp(ROWS_CHUNK / 64, 1);

    // ---- Pass 1: agent attention (tokens = objects, N=64), row order (s,t,o)
    for (int c = 0; c < NCHUNK; ++c) {
        const int rowbase = c * ROWS_CHUNK;
        gemm_mfma<<<gq, 256, 0, stream>>>(x, wqa_h, wqa_l, nullptr,
            nullptr, qkv_h, qkv_l, 1, rowbase, 3 * C_,
            T_ * O_, (long)O_ * T_ * C_,
            O_, T_, (long)C_,
            O_, (long)T_ * C_);
        dim3 ga(SC_ * T_, 2);
        attn_mfma<O_, 4><<<ga, 256, 0, stream>>>(qkv_h, qkv_l, mask,
            out + (long)rowbase * C_, c * SC_ * T_, T_, 1L, (long)T_);
        gemm_mfma<<<gp, 256, 0, stream>>>(out + (long)rowbase * C_, wpa_h, wpa_l, bproj_a,
            out + (long)rowbase * C_, nullptr, nullptr, 0, 0, C_,
            1, (long)C_, 1, 1, 0L, 1, 0L);
    }

    // ---- Pass 2: time attention (tokens = timesteps, N=91), row order (s,o,t)
    for (int c = 0; c < NCHUNK; ++c) {
        const int rowbase = c * ROWS_CHUNK;
        gemm_mfma<<<gq, 256, 0, stream>>>(out, wqt_h, wqt_l, nullptr,
            nullptr, qkv_h, qkv_l, 1, rowbase, 3 * C_,
            O_ * T_, (long)T_ * O_ * C_,
            T_, O_, (long)C_,
            T_, (long)O_ * C_);
        dim3 ga(SC_ * O_, 2);
        attn_mfma<T_, 6><<<ga, 256, 0, stream>>>(qkv_h, qkv_l, mask,
            out + (long)rowbase * C_, c * SC_ * O_, O_, (long)T_, 1L);
        gemm_mfma<<<gp, 256, 0, stream>>>(out + (long)rowbase * C_, wpt_h, wpt_l, bproj_t,
            out + (long)rowbase * C_, nullptr, nullptr, 0, 0, C_,
            1, (long)C_, 1, 1, 0L, 1, 0L);
    }
}

// Round 6
// 328.814 us; speedup vs baseline: 28.2957x; 2.2699x over previous
//
#include <hip/hip_runtime.h>

#define S_ 32
#define O_ 64
#define T_ 91
#define C_ 128
#define H_ 8
#define HD_ 16

typedef __attribute__((ext_vector_type(8))) short short8;
typedef __attribute__((ext_vector_type(4))) short short4b;
typedef __attribute__((ext_vector_type(4))) float f32x4;

__device__ __forceinline__ void splitf(float f, short& h, short& l) {
    unsigned u = __float_as_uint(f);
    float hf = __uint_as_float(u & 0xffff0000u);
    h = (short)(u >> 16);
    l = (short)(__float_as_uint(f - hf) >> 16);
}

__device__ __forceinline__ void split8g(const float* p, short8& h, short8& l) {
    float4 a = *(const float4*)p;
    float4 b = *(const float4*)(p + 4);
    float v[8] = {a.x, a.y, a.z, a.w, b.x, b.y, b.z, b.w};
    #pragma unroll
    for (int j = 0; j < 8; ++j) { short hh, ll; splitf(v[j], hh, ll); h[j] = hh; l[j] = ll; }
}

__device__ __forceinline__ void split4v(f32x4 v, short4b& h, short4b& l) {
    #pragma unroll
    for (int j = 0; j < 4; ++j) { short hh, ll; splitf(v[j], hh, ll); h[j] = hh; l[j] = ll; }
}

// ---------------------------------------------------------------------------
// Fully fused pass: per block = one batch (N tokens, C=128). 8 waves = 8 heads.
// Stage 0: x -> LDS as split-bf16 in 16x16x32-frag-linear layout; mask -> LDS.
// Stage 1: per wave (head h): Q^T = Wq x^T, K^T = Wk x^T, V = x Wv^T via
//          3-term split MFMA; outputs land directly in the operand layouts of
//          stage 2 (S^T = mfma(K, Q) A/B frags, PV B-frag). All in registers.
// Stage 2: attention (round-5 logic): no max-sub softmax, per-lane key bitmasks,
//          sum via shfl_xor(16,32), inv via ds_bpermute; y (f32, post-scale)
//          written to LDS (reusing x region, stride 136), head h owns cols
//          [16h,16h+16).
// Stage 3: proj: y @ Wproj^T + bias via split MFMA; wave w owns output cols
//          [16w,16w+16); coalesced f32 stores to y_out (batch-contiguous rows).
// ---------------------------------------------------------------------------
template<int N, int NT>
__global__ __launch_bounds__(512) void fused_pass(
    const float* __restrict__ xg, const int* __restrict__ mask,
    const float* __restrict__ Wqkv, const float* __restrict__ Wproj,
    const float* __restrict__ bproj, float* __restrict__ yout,
    int bdiv, long bs1, long bs2, long ts, long m1, long m2)
{
    constexpr bool FULL = (NT * 16 == N);
    extern __shared__ char smem[];
    short* xh = (short*)smem;                 // NT*2048 shorts
    short* xl = xh + NT * 2048;               // NT*2048 shorts
    float* ylds = (float*)smem;               // NT*16 x 136 f32 (aliases xh/xl)
    int*   s_m = (int*)(smem + NT * 8704);    // NT*16 ints

    const int tid = threadIdx.x;
    const int wv = tid >> 6, l = tid & 63;
    const int ic = l & 15, g = l >> 4;
    const int b = blockIdx.x;
    const int s = b / bdiv, u = b - s * bdiv;
    const long xbase = (long)s * bs1 + (long)u * bs2;
    const long mbase = (long)s * (O_ * T_) + (long)u * m1;

    // ---- Stage 0: stage x (split, frag-linear) + mask
    for (int gi = tid; gi < NT * 256; gi += 512) {
        int token = gi >> 4, cg = gi & 15;
        int kp = cg >> 2, gg = cg & 3;
        int slot = ((token >> 4) * 4 + kp) * 512 + (gg * 16 + (token & 15)) * 8;
        short8 vh, vl;
        if (FULL || token < N) {
            const float* p = xg + xbase + (long)token * ts + cg * 8;
            split8g(p, vh, vl);
        } else {
            #pragma unroll
            for (int j = 0; j < 8; ++j) { vh[j] = 0; vl[j] = 0; }
        }
        *(short8*)(xh + slot) = vh;
        *(short8*)(xl + slot) = vl;
    }
    for (int idx = tid; idx < NT * 16; idx += 512)
        s_m[idx] = (idx < N) ? (mask[mbase + (long)idx * m2] != 0) : 0;
    __syncthreads();

    // per-lane key bitmasks: key j = jt*16 + 4g + r  -> bit jt*4+r
    unsigned jbits = 0, mbits = 0;
    #pragma unroll
    for (int jt = 0; jt < NT; ++jt)
        #pragma unroll
        for (int r = 0; r < 4; ++r) {
            int j = jt * 16 + 4 * g + r;
            if (j < N) {
                jbits |= 1u << (jt * 4 + r);
                if (s_m[j]) mbits |= 1u << (jt * 4 + r);
            }
        }

    // ---- Stage 1: QKV for head h = wv
    const int h = wv;
    const float* Wqp = Wqkv + (long)(h * 16 + ic) * C_;
    const float* Wkp = Wqkv + (long)(128 + h * 16 + ic) * C_;
    const float* Wvp = Wqkv + (long)(256 + h * 16 + ic) * C_;

    f32x4 aQ[NT], aK[NT], aV[NT];
    #pragma unroll
    for (int t = 0; t < NT; ++t) {
        aQ[t] = (f32x4){0.f,0.f,0.f,0.f};
        aK[t] = (f32x4){0.f,0.f,0.f,0.f};
        aV[t] = (f32x4){0.f,0.f,0.f,0.f};
    }
    #pragma unroll
    for (int kp = 0; kp < 4; ++kp) {
        short8 wqh, wql, wkh, wkl, wvh, wvl;
        split8g(Wqp + kp * 32 + g * 8, wqh, wql);
        split8g(Wkp + kp * 32 + g * 8, wkh, wkl);
        split8g(Wvp + kp * 32 + g * 8, wvh, wvl);
        #pragma unroll
        for (int tt = 0; tt < NT; ++tt) {
            short8 xhv = *(const short8*)(xh + (tt * 4 + kp) * 512 + l * 8);
            short8 xlv = *(const short8*)(xl + (tt * 4 + kp) * 512 + l * 8);
            aQ[tt] = __builtin_amdgcn_mfma_f32_16x16x32_bf16(wqh, xhv, aQ[tt], 0, 0, 0);
            aQ[tt] = __builtin_amdgcn_mfma_f32_16x16x32_bf16(wql, xhv, aQ[tt], 0, 0, 0);
            aQ[tt] = __builtin_amdgcn_mfma_f32_16x16x32_bf16(wqh, xlv, aQ[tt], 0, 0, 0);
            aK[tt] = __builtin_amdgcn_mfma_f32_16x16x32_bf16(wkh, xhv, aK[tt], 0, 0, 0);
            aK[tt] = __builtin_amdgcn_mfma_f32_16x16x32_bf16(wkl, xhv, aK[tt], 0, 0, 0);
            aK[tt] = __builtin_amdgcn_mfma_f32_16x16x32_bf16(wkh, xlv, aK[tt], 0, 0, 0);
            aV[tt] = __builtin_amdgcn_mfma_f32_16x16x32_bf16(xhv, wvh, aV[tt], 0, 0, 0);
            aV[tt] = __builtin_amdgcn_mfma_f32_16x16x32_bf16(xlv, wvh, aV[tt], 0, 0, 0);
            aV[tt] = __builtin_amdgcn_mfma_f32_16x16x32_bf16(xhv, wvl, aV[tt], 0, 0, 0);
        }
    }
    // convert to attention frags (layouts chain without cross-lane movement)
    short4b qfh[NT], qfl[NT], kfh[NT], kfl[NT], vfh[NT], vfl[NT];
    #pragma unroll
    for (int t = 0; t < NT; ++t) {
        split4v(aQ[t], qfh[t], qfl[t]);
        split4v(aK[t], kfh[t], kfl[t]);
        split4v(aV[t], vfh[t], vfl[t]);
    }
    __syncthreads();   // all x reads done; LDS region becomes y

    // ---- Stage 2: attention (head h), query tiles
    for (int it = 0; it < NT; ++it) {
        f32x4 sa[NT];
        #pragma unroll
        for (int jt = 0; jt < NT; ++jt) sa[jt] = (f32x4){0.f,0.f,0.f,0.f};
        #pragma unroll
        for (int jt = 0; jt < NT; ++jt) {
            sa[jt] = __builtin_amdgcn_mfma_f32_16x16x16bf16_1k(kfh[jt], qfh[it], sa[jt], 0, 0, 0);
            sa[jt] = __builtin_amdgcn_mfma_f32_16x16x16bf16_1k(kfl[jt], qfh[it], sa[jt], 0, 0, 0);
            sa[jt] = __builtin_amdgcn_mfma_f32_16x16x16bf16_1k(kfh[jt], qfl[it], sa[jt], 0, 0, 0);
        }
        const int query = it * 16 + ic;
        const bool iok = FULL || (query < N);
        const int qm = iok ? s_m[query] : 0;

        float sum = 0.f;
        short4b ph[NT], pl[NT];
        #pragma unroll
        for (int jt = 0; jt < NT; ++jt) {
            #pragma unroll
            for (int r = 0; r < 4; ++r) {
                int bit = (jt << 2) + r;
                float e;
                if (!iok) e = 0.f;
                else if (!qm) e = ((jbits >> bit) & 1) ? 1.f : 0.f;
                else e = ((mbits >> bit) & 1) ? __expf(sa[jt][r] * 0.25f) : 0.f;
                sum += e;
                short hh, ll; splitf(e, hh, ll);
                ph[jt][r] = hh; pl[jt][r] = ll;
            }
        }
        sum += __shfl_xor(sum, 16, 64);
        sum += __shfl_xor(sum, 32, 64);
        const float inv = 1.f / sum;

        f32x4 pv = (f32x4){0.f,0.f,0.f,0.f};
        #pragma unroll
        for (int kt = 0; kt < NT; ++kt) {
            pv = __builtin_amdgcn_mfma_f32_16x16x16bf16_1k(ph[kt], vfh[kt], pv, 0, 0, 0);
            pv = __builtin_amdgcn_mfma_f32_16x16x16bf16_1k(pl[kt], vfh[kt], pv, 0, 0, 0);
            pv = __builtin_amdgcn_mfma_f32_16x16x16bf16_1k(ph[kt], vfl[kt], pv, 0, 0, 0);
        }
        #pragma unroll
        for (int r = 0; r < 4; ++r) {
            int rloc = 4 * g + r;
            int row = it * 16 + rloc;
            int iv = __builtin_amdgcn_ds_bpermute(rloc << 2, __float_as_int(inv));
            if (FULL || row < N)
                ylds[row * 136 + h * 16 + ic] = pv[r] * __int_as_float(iv);
        }
    }
    __syncthreads();   // y complete

    // ---- Stage 3: proj; wave wv owns output cols [16wv, 16wv+16)
    const float* Wpr = Wproj + (long)(wv * 16 + ic) * C_;
    short8 pwh[4], pwl[4];
    #pragma unroll
    for (int kp = 0; kp < 4; ++kp) split8g(Wpr + kp * 32 + g * 8, pwh[kp], pwl[kp]);
    const float bv = bproj[wv * 16 + ic];

    #pragma unroll
    for (int mt = 0; mt < NT; ++mt) {
        f32x4 acc = (f32x4){0.f,0.f,0.f,0.f};
        #pragma unroll
        for (int kp = 0; kp < 4; ++kp) {
            const float* yp = ylds + (mt * 16 + ic) * 136 + kp * 32 + g * 8;
            short8 ayh, ayl;
            split8g(yp, ayh, ayl);
            acc = __builtin_amdgcn_mfma_f32_16x16x32_bf16(ayh, pwh[kp], acc, 0, 0, 0);
            acc = __builtin_amdgcn_mfma_f32_16x16x32_bf16(ayl, pwh[kp], acc, 0, 0, 0);
            acc = __builtin_amdgcn_mfma_f32_16x16x32_bf16(ayh, pwl[kp], acc, 0, 0, 0);
        }
        #pragma unroll
        for (int r = 0; r < 4; ++r) {
            int row = mt * 16 + 4 * g + r;
            if (FULL || row < N)
                yout[((long)b * N + row) * C_ + wv * 16 + ic] = acc[r] + bv;
        }
    }
}

extern "C" void kernel_launch(void* const* d_in, const int* in_sizes, int n_in,
                              void* d_out, int out_size, void* d_ws, size_t ws_size,
                              hipStream_t stream) {
    const float* x       = (const float*)d_in[0];
    const int*   mask    = (const int*)d_in[1];
    const float* Wqkv_a  = (const float*)d_in[2];
    const float* Wproj_a = (const float*)d_in[3];
    const float* bproj_a = (const float*)d_in[4];
    const float* Wqkv_t  = (const float*)d_in[5];
    const float* Wproj_t = (const float*)d_in[6];
    const float* bproj_t = (const float*)d_in[7];
    float* out = (float*)d_out;
    float* xa  = (float*)d_ws;   // pass-1 output, (s,t,o,c) f32, 95.4 MB

    // Pass 1: agent attention. batch b=(s,t), tokens = objects (N=64).
    // x row (s, token=o, t): off = s*OTC + t*C + token*(T*C). mask[s][o][t]: u=t.
    {
        const size_t lds = 4 * 8704 + 4 * 64;   // 35,072 B
        fused_pass<O_, 4><<<S_ * T_, 512, lds, stream>>>(
            x, mask, Wqkv_a, Wproj_a, bproj_a, xa,
            T_, (long)O_ * T_ * C_, (long)C_, (long)T_ * C_,
            1L, (long)T_);
    }
    // Pass 2: time attention. batch b=(s,o), tokens = timesteps (N=91).
    // xa row (s, token=t, o): off = s*TOC + o*C + token*(O*C). mask: u=o.
    {
        const size_t lds = 6 * 8704 + 6 * 64;   // 52,608 B
        fused_pass<T_, 6><<<S_ * O_, 512, lds, stream>>>(
            xa, mask, Wqkv_t, Wproj_t, bproj_t, out,
            O_, (long)T_ * O_ * C_, (long)C_, (long)O_ * C_,
            (long)T_, 1L);
    }
}

// Round 7
// 313.705 us; speedup vs baseline: 29.6585x; 1.0482x over previous
//
#include <hip/hip_runtime.h>

#define S_ 32
#define O_ 64
#define T_ 91
#define C_ 128
#define H_ 8

typedef __attribute__((ext_vector_type(8))) short short8;
typedef __attribute__((ext_vector_type(4))) short short4b;
typedef __attribute__((ext_vector_type(4))) float f32x4;

// Pre-split weights (bf16 hi/lo, MFMA-frag-linear), written by prep_all each call.
__device__ short g_wqa_h[384 * 128], g_wqa_l[384 * 128];
__device__ short g_wqt_h[384 * 128], g_wqt_l[384 * 128];
__device__ short g_wpa_h[128 * 128], g_wpa_l[128 * 128];
__device__ short g_wpt_h[128 * 128], g_wpt_l[128 * 128];

__device__ __forceinline__ void splitf(float f, short& h, short& l) {
    unsigned u = __float_as_uint(f);
    float hf = __uint_as_float(u & 0xffff0000u);
    h = (short)(u >> 16);
    l = (short)(__float_as_uint(f - hf) >> 16);
}

__device__ __forceinline__ void split8g(const float* p, short8& h, short8& l) {
    float4 a = *(const float4*)p;
    float4 b = *(const float4*)(p + 4);
    float v[8] = {a.x, a.y, a.z, a.w, b.x, b.y, b.z, b.w};
    #pragma unroll
    for (int j = 0; j < 8; ++j) { short hh, ll; splitf(v[j], hh, ll); h[j] = hh; l[j] = ll; }
}

__device__ __forceinline__ void split4v(f32x4 v, short4b& h, short4b& l) {
    #pragma unroll
    for (int j = 0; j < 4; ++j) { short hh, ll; splitf(v[j], hh, ll); h[j] = hh; l[j] = ll; }
}

// ---------------------------------------------------------------------------
// Weight prep: all four matrices -> hi/lo bf16, frag-linear:
// element (c,k): ct=c>>4, cl=c&15, kp=k>>5, gg=(k>>3)&3, j=k&7
//   slot = ct*2048 + kp*512 + (cl+16*gg)*8 + j
// ---------------------------------------------------------------------------
__global__ __launch_bounds__(256) void prep_all(
    const float* __restrict__ wqa, const float* __restrict__ wqt,
    const float* __restrict__ wpa, const float* __restrict__ wpt)
{
    int t = blockIdx.x * 256 + threadIdx.x;     // 16384 total
    const float* src; short* dh; short* dl; int idx;
    if (t < 6144)       { src = wqa; dh = g_wqa_h; dl = g_wqa_l; idx = t; }
    else if (t < 12288) { src = wqt; dh = g_wqt_h; dl = g_wqt_l; idx = t - 6144; }
    else if (t < 14336) { src = wpa; dh = g_wpa_h; dl = g_wpa_l; idx = t - 12288; }
    else                { src = wpt; dh = g_wpt_h; dl = g_wpt_l; idx = t - 14336; }
    int c = idx >> 4, gk = idx & 15;
    int kp = gk >> 2, gg = gk & 3;
    int ct = c >> 4, cl = c & 15;
    const float* s = src + (long)c * C_ + gk * 8;
    long slot = (long)ct * 2048 + kp * 512 + (cl + 16 * gg) * 8;
    short8 vh, vl;
    split8g(s, vh, vl);
    *(short8*)(dh + slot) = vh;
    *(short8*)(dl + slot) = vl;
}

// ---------------------------------------------------------------------------
// Fused pass (QKV + masked attention + proj). Block = one batch, 8 waves = heads.
// PASS selects the weight set (0: agent, 1: time).
// Stage 0: x -> LDS split bf16, frag-linear. Stage 1: QKV via split MFMA with
// pre-split weights; Q scaled by 0.25*log2e before split. Stage 2: S^T=mfma(K,Q),
// exp2-softmax (no max-sub), P->RNE bf16 (hi only), PV = ph*(vh+vl); y written
// to LDS as split bf16 frag-linear. Stage 3: proj, 3-term split MFMA, f32 out.
// ---------------------------------------------------------------------------
template<int N, int NT, int PASS>
__global__ __launch_bounds__(512) void fused_pass(
    const float* __restrict__ xg, const int* __restrict__ mask,
    const float* __restrict__ bproj, float* __restrict__ yout,
    int bdiv, long bs1, long bs2, long ts, long m1, long m2)
{
    constexpr bool FULL = (NT * 16 == N);
    extern __shared__ char smem[];
    short* xh = (short*)smem;                       // NT*2048 shorts
    short* xl = xh + NT * 2048;                     // NT*2048 shorts
    short* yh = xh;                                 // aliases x region (after sync)
    short* yl = xl;
    int*   s_m = (int*)(smem + NT * 8192);          // NT*16 ints

    const short* Wh = (PASS == 0) ? g_wqa_h : g_wqt_h;
    const short* Wl = (PASS == 0) ? g_wqa_l : g_wqt_l;
    const short* Ph = (PASS == 0) ? g_wpa_h : g_wpt_h;
    const short* Pl = (PASS == 0) ? g_wpa_l : g_wpt_l;

    const int tid = threadIdx.x;
    const int wv = tid >> 6, l = tid & 63;
    const int ic = l & 15, g = l >> 4;
    const int b = blockIdx.x;
    const int s = b / bdiv, u = b - s * bdiv;
    const long xbase = (long)s * bs1 + (long)u * bs2;
    const long mbase = (long)s * (O_ * T_) + (long)u * m1;

    // ---- Stage 0: stage x (split, frag-linear) + mask
    for (int gi = tid; gi < NT * 256; gi += 512) {
        int token = gi >> 4, cg = gi & 15;
        int kp = cg >> 2, gg = cg & 3;
        int slot = ((token >> 4) * 4 + kp) * 512 + (gg * 16 + (token & 15)) * 8;
        short8 vh, vl;
        if (FULL || token < N) {
            split8g(xg + xbase + (long)token * ts + cg * 8, vh, vl);
        } else {
            #pragma unroll
            for (int j = 0; j < 8; ++j) { vh[j] = 0; vl[j] = 0; }
        }
        *(short8*)(xh + slot) = vh;
        *(short8*)(xl + slot) = vl;
    }
    for (int idx = tid; idx < NT * 16; idx += 512)
        s_m[idx] = (idx < N) ? (mask[mbase + (long)idx * m2] != 0) : 0;
    __syncthreads();

    // per-lane key bitmasks: key j = jt*16 + 4g + r -> bit jt*4+r
    unsigned jbits = 0, mbits = 0;
    #pragma unroll
    for (int jt = 0; jt < NT; ++jt)
        #pragma unroll
        for (int r = 0; r < 4; ++r) {
            int j = jt * 16 + 4 * g + r;
            if (j < N) {
                jbits |= 1u << (jt * 4 + r);
                if (s_m[j]) mbits |= 1u << (jt * 4 + r);
            }
        }

    // ---- Stage 1: QKV for head h = wv (pre-split weights)
    const int h = wv;
    f32x4 aQ[NT], aK[NT], aV[NT];
    #pragma unroll
    for (int t2 = 0; t2 < NT; ++t2) {
        aQ[t2] = (f32x4){0.f,0.f,0.f,0.f};
        aK[t2] = (f32x4){0.f,0.f,0.f,0.f};
        aV[t2] = (f32x4){0.f,0.f,0.f,0.f};
    }
    #pragma unroll
    for (int kp = 0; kp < 4; ++kp) {
        short8 wqh = *(const short8*)(Wh + (h * 4 + kp) * 512 + l * 8);
        short8 wql = *(const short8*)(Wl + (h * 4 + kp) * 512 + l * 8);
        short8 wkh = *(const short8*)(Wh + ((8 + h) * 4 + kp) * 512 + l * 8);
        short8 wkl = *(const short8*)(Wl + ((8 + h) * 4 + kp) * 512 + l * 8);
        short8 wvh = *(const short8*)(Wh + ((16 + h) * 4 + kp) * 512 + l * 8);
        short8 wvl = *(const short8*)(Wl + ((16 + h) * 4 + kp) * 512 + l * 8);
        #pragma unroll
        for (int tt = 0; tt < NT; ++tt) {
            short8 xhv = *(const short8*)(xh + (tt * 4 + kp) * 512 + l * 8);
            short8 xlv = *(const short8*)(xl + (tt * 4 + kp) * 512 + l * 8);
            aQ[tt] = __builtin_amdgcn_mfma_f32_16x16x32_bf16(wqh, xhv, aQ[tt], 0, 0, 0);
            aQ[tt] = __builtin_amdgcn_mfma_f32_16x16x32_bf16(wql, xhv, aQ[tt], 0, 0, 0);
            aQ[tt] = __builtin_amdgcn_mfma_f32_16x16x32_bf16(wqh, xlv, aQ[tt], 0, 0, 0);
            aK[tt] = __builtin_amdgcn_mfma_f32_16x16x32_bf16(wkh, xhv, aK[tt], 0, 0, 0);
            aK[tt] = __builtin_amdgcn_mfma_f32_16x16x32_bf16(wkl, xhv, aK[tt], 0, 0, 0);
            aK[tt] = __builtin_amdgcn_mfma_f32_16x16x32_bf16(wkh, xlv, aK[tt], 0, 0, 0);
            aV[tt] = __builtin_amdgcn_mfma_f32_16x16x32_bf16(xhv, wvh, aV[tt], 0, 0, 0);
            aV[tt] = __builtin_amdgcn_mfma_f32_16x16x32_bf16(xlv, wvh, aV[tt], 0, 0, 0);
            aV[tt] = __builtin_amdgcn_mfma_f32_16x16x32_bf16(xhv, wvl, aV[tt], 0, 0, 0);
        }
    }
    // frags for attention; fold softmax scale (0.25 * log2 e) into Q
    const float QS = 0.25f * 1.44269504088896f;
    short4b qfh[NT], qfl[NT], kfh[NT], kfl[NT], vfh[NT], vfl[NT];
    #pragma unroll
    for (int t2 = 0; t2 < NT; ++t2) {
        f32x4 qs = aQ[t2] * QS;
        split4v(qs, qfh[t2], qfl[t2]);
        split4v(aK[t2], kfh[t2], kfl[t2]);
        split4v(aV[t2], vfh[t2], vfl[t2]);
    }
    // proj weight frags (independent loads; scheduler hoists)
    short8 pwh[4], pwl[4];
    #pragma unroll
    for (int kp = 0; kp < 4; ++kp) {
        pwh[kp] = *(const short8*)(Ph + (wv * 4 + kp) * 512 + l * 8);
        pwl[kp] = *(const short8*)(Pl + (wv * 4 + kp) * 512 + l * 8);
    }
    __syncthreads();   // x reads done; LDS region becomes y (split bf16)

    // y-slot constants for this wave's columns c = 16*wv + ic
    const int kpw = wv >> 1;
    const int ggw = (2 * wv + (ic >> 3)) & 3;
    const int jw  = ic & 7;

    // ---- Stage 2: attention
    #pragma unroll
    for (int it = 0; it < NT; ++it) {
        f32x4 sa[NT];
        #pragma unroll
        for (int jt = 0; jt < NT; ++jt) sa[jt] = (f32x4){0.f,0.f,0.f,0.f};
        #pragma unroll
        for (int jt = 0; jt < NT; ++jt) {
            sa[jt] = __builtin_amdgcn_mfma_f32_16x16x16bf16_1k(kfh[jt], qfh[it], sa[jt], 0, 0, 0);
            sa[jt] = __builtin_amdgcn_mfma_f32_16x16x16bf16_1k(kfl[jt], qfh[it], sa[jt], 0, 0, 0);
            sa[jt] = __builtin_amdgcn_mfma_f32_16x16x16bf16_1k(kfh[jt], qfl[it], sa[jt], 0, 0, 0);
        }
        const int query = it * 16 + ic;
        const int qm = s_m[query];                   // padded: 0 for query >= N
        const unsigned msel = qm ? mbits : jbits;
        float sum = 0.f;
        short4b ph[NT];
        #pragma unroll
        for (int jt = 0; jt < NT; ++jt) {
            #pragma unroll
            for (int r = 0; r < 4; ++r) {
                int bit = (jt << 2) + r;
                float inner = qm ? sa[jt][r] : 0.f;  // dead row: exp2(0)=1 over valid keys
                float xv = ((msel >> bit) & 1u) ? inner : -1e30f;
                float e = exp2f(xv);
                sum += e;
                unsigned ue = __float_as_uint(e);    // RNE to bf16
                ue += 0x7fffu + ((ue >> 16) & 1u);
                ph[jt][r] = (short)(ue >> 16);
            }
        }
        sum += __shfl_xor(sum, 16, 64);
        sum += __shfl_xor(sum, 32, 64);
        const float inv = 1.f / sum;

        f32x4 pv = (f32x4){0.f,0.f,0.f,0.f};
        #pragma unroll
        for (int kt = 0; kt < NT; ++kt) {
            pv = __builtin_amdgcn_mfma_f32_16x16x16bf16_1k(ph[kt], vfh[kt], pv, 0, 0, 0);
            pv = __builtin_amdgcn_mfma_f32_16x16x16bf16_1k(ph[kt], vfl[kt], pv, 0, 0, 0);
        }
        #pragma unroll
        for (int r = 0; r < 4; ++r) {
            int rloc = 4 * g + r;
            int row = it * 16 + rloc;
            int iv = __builtin_amdgcn_ds_bpermute(rloc << 2, __float_as_int(inv));
            float yv = pv[r] * __int_as_float(iv);
            short hh = 0, ll = 0;
            if (FULL || row < N) splitf(yv, hh, ll);
            int slot = (it * 4 + kpw) * 512 + (ggw * 16 + rloc) * 8 + jw;
            yh[slot] = hh;
            yl[slot] = ll;
        }
    }
    __syncthreads();   // y complete (split bf16, frag-linear)

    // ---- Stage 3: proj; wave wv owns output cols [16wv, 16wv+16)
    const float bv = bproj[wv * 16 + ic];
    #pragma unroll
    for (int mt = 0; mt < NT; ++mt) {
        f32x4 acc = (f32x4){0.f,0.f,0.f,0.f};
        #pragma unroll
        for (int kp = 0; kp < 4; ++kp) {
            short8 ayh = *(const short8*)(yh + (mt * 4 + kp) * 512 + l * 8);
            short8 ayl = *(const short8*)(yl + (mt * 4 + kp) * 512 + l * 8);
            acc = __builtin_amdgcn_mfma_f32_16x16x32_bf16(ayh, pwh[kp], acc, 0, 0, 0);
            acc = __builtin_amdgcn_mfma_f32_16x16x32_bf16(ayl, pwh[kp], acc, 0, 0, 0);
            acc = __builtin_amdgcn_mfma_f32_16x16x32_bf16(ayh, pwl[kp], acc, 0, 0, 0);
        }
        #pragma unroll
        for (int r = 0; r < 4; ++r) {
            int row = mt * 16 + 4 * g + r;
            if (FULL || row < N)
                yout[((long)b * N + row) * C_ + wv * 16 + ic] = acc[r] + bv;
        }
    }
}

extern "C" void kernel_launch(void* const* d_in, const int* in_sizes, int n_in,
                              void* d_out, int out_size, void* d_ws, size_t ws_size,
                              hipStream_t stream) {
    const float* x       = (const float*)d_in[0];
    const int*   mask    = (const int*)d_in[1];
    const float* Wqkv_a  = (const float*)d_in[2];
    const float* bproj_a = (const float*)d_in[4];
    const float* Wqkv_t  = (const float*)d_in[5];
    const float* bproj_t = (const float*)d_in[7];
    const float* Wproj_a = (const float*)d_in[3];
    const float* Wproj_t = (const float*)d_in[6];
    float* out = (float*)d_out;
    float* xa  = (float*)d_ws;   // pass-1 output, (s,t,o,c) f32, 95.4 MB

    prep_all<<<64, 256, 0, stream>>>(Wqkv_a, Wqkv_t, Wproj_a, Wproj_t);

    // Pass 1: agent attention. batch (s,t), tokens = objects (N=64).
    {
        const size_t lds = 4 * 8192 + 4 * 64;
        fused_pass<O_, 4, 0><<<S_ * T_, 512, lds, stream>>>(
            x, mask, bproj_a, xa,
            T_, (long)O_ * T_ * C_, (long)C_, (long)T_ * C_,
            1L, (long)T_);
    }
    // Pass 2: time attention. batch (s,o), tokens = timesteps (N=91).
    {
        const size_t lds = 6 * 8192 + 6 * 64;
        fused_pass<T_, 6, 1><<<S_ * O_, 512, lds, stream>>>(
            xa, mask, bproj_t, out,
            O_, (long)T_ * O_ * C_, (long)C_, (long)O_ * C_,
            (long)T_, 1L);
    }
}